// Round 2
// baseline (1183.357 us; speedup 1.0000x reference)
//
#include <hip/hip_runtime.h>

#define E_EDGES 320000
#define N_NODES 10000
#define DEG_CAP 128

typedef __attribute__((ext_vector_type(8))) short bf16x8;
typedef __attribute__((ext_vector_type(4))) float f32x4;

__device__ __forceinline__ unsigned short f2bf(float x) {
  union { float f; unsigned u; } v; v.f = x;
  unsigned r = v.u + 0x7FFFu + ((v.u >> 16) & 1u);
  return (unsigned short)(r >> 16);
}
__device__ __forceinline__ float bf2f(unsigned short s) {
  union { unsigned u; float f; } v; v.u = ((unsigned)s) << 16;
  return v.f;
}

// ---------------- prep: W1 -> W1at/W1bt bf16 [n][k], W2 -> W2t bf16 [n][k] ----
__global__ __launch_bounds__(256) void prep_kernel(
    const float* __restrict__ W1, const float* __restrict__ W2,
    unsigned short* __restrict__ W1at, unsigned short* __restrict__ W1bt,
    unsigned short* __restrict__ W2t) {
  int tid = blockIdx.x * 256 + threadIdx.x;
  if (tid < 512 * 256) {
    int n = tid >> 8, k = tid & 255;          // W1at/W1bt: [512 n][256 k]
    W1at[tid] = f2bf(W1[k * 512 + n]);
    W1bt[tid] = f2bf(W1[(k + 256) * 512 + n]);
  } else {
    int t = tid - 512 * 256;
    if (t < 256 * 512) {
      int n = t >> 9, k = t & 511;            // W2t: [256 n][512 k]
      W2t[t] = f2bf(W2[k * 256 + n]);
    }
  }
}

// ---------------- U = x_in @ W1[0:256,:] + b1 (merged with CSR build) --------
// blocks [0,628): U GEMM (bx = b%157 nodes, by = b/157 col-chunk)
// blocks [628,1878): CSR histogram+perm
__global__ __launch_bounds__(256) void u_csr_kernel(
    const float* __restrict__ x_in, const unsigned short* __restrict__ W1at,
    const float* __restrict__ b1, unsigned short* __restrict__ U,
    const int* __restrict__ EI, int* __restrict__ cnt, int* __restrict__ perm) {
  int b = blockIdx.x;
  if (b >= 628) {
    int e = (b - 628) * 256 + threadIdx.x;
    if (e < E_EDGES) {
      int d = EI[e];
      d = min(max(d, 0), N_NODES - 1);
      int p = atomicAdd(cnt + d, 1);
      if (p < DEG_CAP) perm[d * DEG_CAP + p] = e;
    }
    return;
  }
  int bx = b % 157, by = b / 157;
  __shared__ unsigned short x_lds[64 * 264];
  int tid = threadIdx.x;
  int m0g = bx * 64;
  for (int it = 0; it < 16; ++it) {
    int i = it * 256 + tid;
    int r = i >> 6, c = i & 63;
    int node = m0g + r;
    float4 v = make_float4(0.f, 0.f, 0.f, 0.f);
    if (node < N_NODES) v = *(const float4*)(x_in + node * 256 + c * 4);
    ushort4 s4;
    s4.x = f2bf(v.x); s4.y = f2bf(v.y); s4.z = f2bf(v.z); s4.w = f2bf(v.w);
    *(ushort4*)(x_lds + r * 264 + c * 4) = s4;
  }
  __syncthreads();
  int w = tid >> 6, l = tid & 63, quad = l >> 4, lid = l & 15;
  int cb = by * 128 + w * 32;
  f32x4 acc[2][4];
#pragma unroll
  for (int a = 0; a < 2; ++a)
#pragma unroll
    for (int c = 0; c < 4; ++c) acc[a][c] = (f32x4){0.f, 0.f, 0.f, 0.f};
  bf16x8 ac[2], an[2];
#pragma unroll
  for (int mf2 = 0; mf2 < 2; ++mf2)
    ac[mf2] = *(const bf16x8*)(W1at + (size_t)(cb + mf2 * 16 + lid) * 256 + quad * 8);
#pragma unroll
  for (int kk = 0; kk < 8; ++kk) {
    if (kk < 7) {
#pragma unroll
      for (int mf2 = 0; mf2 < 2; ++mf2)
        an[mf2] = *(const bf16x8*)(W1at + (size_t)(cb + mf2 * 16 + lid) * 256 + (kk + 1) * 32 + quad * 8);
    }
    bf16x8 xf[4];
#pragma unroll
    for (int nf2 = 0; nf2 < 4; ++nf2)
      xf[nf2] = *(const bf16x8*)(x_lds + (nf2 * 16 + lid) * 264 + kk * 32 + quad * 8);
#pragma unroll
    for (int mf2 = 0; mf2 < 2; ++mf2)
#pragma unroll
      for (int nf2 = 0; nf2 < 4; ++nf2)
        acc[mf2][nf2] = __builtin_amdgcn_mfma_f32_16x16x32_bf16(ac[mf2], xf[nf2], acc[mf2][nf2], 0, 0, 0);
#pragma unroll
    for (int mf2 = 0; mf2 < 2; ++mf2) ac[mf2] = an[mf2];
  }
#pragma unroll
  for (int mf2 = 0; mf2 < 2; ++mf2) {
    int colb = cb + mf2 * 16 + quad * 4;
    float4 bv = *(const float4*)(b1 + colb);
#pragma unroll
    for (int nf2 = 0; nf2 < 4; ++nf2) {
      int node = m0g + nf2 * 16 + lid;
      if (node < N_NODES) {
        ushort4 s4;
        s4.x = f2bf(acc[mf2][nf2][0] + bv.x);
        s4.y = f2bf(acc[mf2][nf2][1] + bv.y);
        s4.z = f2bf(acc[mf2][nf2][2] + bv.z);
        s4.w = f2bf(acc[mf2][nf2][3] + bv.w);
        *(ushort4*)(U + (size_t)node * 512 + colb) = s4;
      }
    }
  }
}

// ---------------- fused edge MLP: 128-thread / 32-edge blocks ----------------
// 2 waves per block; 6 blocks/CU (LDS 25.9KB) for phase-decorrelated latency
// hiding. Same per-wave MFMA mix as the 64-edge version.
#define EA_OFF 0                      // 32 x 264 shorts = 16896 B
#define H_OFF  (32 * 264)             // 32 x 136 shorts = 8704 B
#define IDX_OFF (H_OFF + 32 * 136)    // 64 ints = 256 B
template <int USE_MSGS>
__global__ __launch_bounds__(128, 3) void main_kernel(
    const int* __restrict__ EI, const float* __restrict__ edge_attr,
    const unsigned short* __restrict__ W1bt, const unsigned short* __restrict__ W2t,
    const unsigned short* __restrict__ U, const float* __restrict__ b2,
    float* __restrict__ out, unsigned short* __restrict__ msgs) {
  __shared__ unsigned short lds[32 * 264 + 32 * 136 + 128];
  int* idx_lds = (int*)(lds + IDX_OFF);   // [0..31]=dst, [32..63]=src

  int tid = threadIdx.x;
  int e0 = blockIdx.x * 32;
  if (tid < 32) {
    int d = EI[e0 + tid];
    idx_lds[tid] = min(max(d, 0), N_NODES - 1);
  } else if (tid < 64) {
    int s = EI[E_EDGES + e0 + (tid - 32)];
    idx_lds[tid] = min(max(s, 0), N_NODES - 1);
  }
  for (int it = 0; it < 16; ++it) {
    int i = it * 128 + tid;
    int r = i >> 6, c = i & 63;
    float4 v = *(const float4*)(edge_attr + (size_t)(e0 + r) * 256 + c * 4);
    ushort4 s4;
    s4.x = f2bf(v.x); s4.y = f2bf(v.y); s4.z = f2bf(v.z); s4.w = f2bf(v.w);
    *(ushort4*)(lds + EA_OFF + r * 264 + c * 4) = s4;
  }
  __syncthreads();

  int w = tid >> 6, l = tid & 63, quad = l >> 4, lid = l & 15;

  f32x4 macc[8][2];   // [outcol-frag (128 cols/wave)][edge-frag (32 edges)]
#pragma unroll
  for (int a = 0; a < 8; ++a)
#pragma unroll
    for (int c = 0; c < 2; ++c) macc[a][c] = (f32x4){0.f, 0.f, 0.f, 0.f};

  for (int nc = 0; nc < 4; ++nc) {
    int n0 = nc * 128;
    // ---- U prefetch: 8 x ushort4 (4 contiguous hidden per lane) ----
    ushort4 uq[4][2];
#pragma unroll
    for (int nf2 = 0; nf2 < 2; ++nf2) {
      int src = idx_lds[32 + nf2 * 16 + lid];
      const unsigned short* up = U + (size_t)src * 512 + n0 + w * 64 + quad * 4;
#pragma unroll
      for (int mf2 = 0; mf2 < 4; ++mf2)
        uq[mf2][nf2] = *(const ushort4*)(up + mf2 * 16);
    }
    // ---- GEMM1b (swapped): acc1[hidden-frag (64/wave)][edge-frag] ----
    f32x4 acc1[4][2];
#pragma unroll
    for (int a = 0; a < 4; ++a)
#pragma unroll
      for (int c = 0; c < 2; ++c) acc1[a][c] = (f32x4){0.f, 0.f, 0.f, 0.f};
    int arow = n0 + w * 64 + lid;
    bf16x8 a1c[4], a1n[4];
#pragma unroll
    for (int mf2 = 0; mf2 < 4; ++mf2)
      a1c[mf2] = *(const bf16x8*)(W1bt + (size_t)(arow + mf2 * 16) * 256 + quad * 8);
#pragma unroll
    for (int s = 0; s < 8; ++s) {
      if (s < 7) {
#pragma unroll
        for (int mf2 = 0; mf2 < 4; ++mf2)
          a1n[mf2] = *(const bf16x8*)(W1bt + (size_t)(arow + mf2 * 16) * 256 + (s + 1) * 32 + quad * 8);
      }
      int ka = s * 32 + quad * 8;
      bf16x8 ef[2];
#pragma unroll
      for (int nf2 = 0; nf2 < 2; ++nf2)
        ef[nf2] = *(const bf16x8*)(lds + EA_OFF + (nf2 * 16 + lid) * 264 + ka);
#pragma unroll
      for (int mf2 = 0; mf2 < 4; ++mf2)
#pragma unroll
        for (int nf2 = 0; nf2 < 2; ++nf2)
          acc1[mf2][nf2] = __builtin_amdgcn_mfma_f32_16x16x32_bf16(a1c[mf2], ef[nf2], acc1[mf2][nf2], 0, 0, 0);
#pragma unroll
      for (int mf2 = 0; mf2 < 4; ++mf2) a1c[mf2] = a1n[mf2];
    }
    // ---- epilogue1: h = relu(acc1 + U[src]); pack -> 8B LDS writes ----
    unsigned hp[4][2][2];
#pragma unroll
    for (int mf2 = 0; mf2 < 4; ++mf2)
#pragma unroll
      for (int nf2 = 0; nf2 < 2; ++nf2) {
        ushort4 u4 = uq[mf2][nf2];
        float h0 = acc1[mf2][nf2][0] + bf2f(u4.x);
        float h1 = acc1[mf2][nf2][1] + bf2f(u4.y);
        float h2 = acc1[mf2][nf2][2] + bf2f(u4.z);
        float h3 = acc1[mf2][nf2][3] + bf2f(u4.w);
        h0 = h0 > 0.f ? h0 : 0.f;
        h1 = h1 > 0.f ? h1 : 0.f;
        h2 = h2 > 0.f ? h2 : 0.f;
        h3 = h3 > 0.f ? h3 : 0.f;
        hp[mf2][nf2][0] = (unsigned)f2bf(h0) | ((unsigned)f2bf(h1) << 16);
        hp[mf2][nf2][1] = (unsigned)f2bf(h2) | ((unsigned)f2bf(h3) << 16);
      }
    __syncthreads();   // prev chunk's GEMM2 readers of h done
#pragma unroll
    for (int mf2 = 0; mf2 < 4; ++mf2)
#pragma unroll
      for (int nf2 = 0; nf2 < 2; ++nf2) {
        uint2 d;
        d.x = hp[mf2][nf2][0]; d.y = hp[mf2][nf2][1];
        *(uint2*)(lds + H_OFF + (nf2 * 16 + lid) * 136 + w * 64 + mf2 * 16 + quad * 4) = d;
      }
    __syncthreads();   // h visible
    // ---- GEMM2 (swapped): macc[outcol-frag][edge-frag] += W2t x h ----
    int orow = w * 128 + lid;
    bf16x8 c2[8], n2[8];
#pragma unroll
    for (int mf2 = 0; mf2 < 8; ++mf2)
      c2[mf2] = *(const bf16x8*)(W2t + (size_t)(orow + mf2 * 16) * 512 + n0 + quad * 8);
#pragma unroll
    for (int s2 = 0; s2 < 4; ++s2) {
      if (s2 < 3) {
#pragma unroll
        for (int mf2 = 0; mf2 < 8; ++mf2)
          n2[mf2] = *(const bf16x8*)(W2t + (size_t)(orow + mf2 * 16) * 512 + n0 + (s2 + 1) * 32 + quad * 8);
      }
      int kl = s2 * 32 + quad * 8;
      bf16x8 hf[2];
#pragma unroll
      for (int nf2 = 0; nf2 < 2; ++nf2)
        hf[nf2] = *(const bf16x8*)(lds + H_OFF + (nf2 * 16 + lid) * 136 + kl);
#pragma unroll
      for (int mf2 = 0; mf2 < 8; ++mf2)
#pragma unroll
        for (int nf2 = 0; nf2 < 2; ++nf2)
          macc[mf2][nf2] = __builtin_amdgcn_mfma_f32_16x16x32_bf16(c2[mf2], hf[nf2], macc[mf2][nf2], 0, 0, 0);
#pragma unroll
      for (int mf2 = 0; mf2 < 8; ++mf2) c2[mf2] = n2[mf2];
    }
  }
  // ---- epilogue2 ----
  if (USE_MSGS) {
#pragma unroll
    for (int nf2 = 0; nf2 < 2; ++nf2) {
      size_t ebase = (size_t)(e0 + nf2 * 16 + lid) * 256;
#pragma unroll
      for (int mf2 = 0; mf2 < 8; ++mf2) {
        int col = w * 128 + mf2 * 16 + quad * 4;
        ushort4 s4;
        s4.x = f2bf(macc[mf2][nf2][0]);
        s4.y = f2bf(macc[mf2][nf2][1]);
        s4.z = f2bf(macc[mf2][nf2][2]);
        s4.w = f2bf(macc[mf2][nf2][3]);
        *(ushort4*)(msgs + ebase + col) = s4;
      }
    }
  } else {
#pragma unroll
    for (int mf2 = 0; mf2 < 8; ++mf2) {
      int col = w * 128 + mf2 * 16 + quad * 4;
      float4 bv = *(const float4*)(b2 + col);
#pragma unroll
      for (int nf2 = 0; nf2 < 2; ++nf2) {
        int node = idx_lds[nf2 * 16 + lid];
        float* op = out + (size_t)node * 256 + col;
        atomicAdd(op + 0, macc[mf2][nf2][0] + bv.x);
        atomicAdd(op + 1, macc[mf2][nf2][1] + bv.y);
        atomicAdd(op + 2, macc[mf2][nf2][2] + bv.z);
        atomicAdd(op + 3, macc[mf2][nf2][3] + bv.w);
      }
    }
  }
}

// ---------------- aggregation: wave-per-node, 4 gathers in flight ------------
__global__ __launch_bounds__(256) void agg_kernel(
    const unsigned short* __restrict__ msgs, const int* __restrict__ perm,
    const int* __restrict__ cnt, const float* __restrict__ b2,
    float* __restrict__ out) {
  int wv = threadIdx.x >> 6, lane = threadIdx.x & 63;
  int node = blockIdx.x * 4 + wv;
  int c = min(cnt[node], DEG_CAP);
  const int* pl = perm + node * DEG_CAP;
  float a0 = 0.f, a1 = 0.f, a2 = 0.f, a3 = 0.f;
  int i = 0;
  for (; i + 4 <= c; i += 4) {
    int4 e4 = *(const int4*)(pl + i);
    ushort4 v0 = *(const ushort4*)(msgs + (size_t)e4.x * 256 + lane * 4);
    ushort4 v1 = *(const ushort4*)(msgs + (size_t)e4.y * 256 + lane * 4);
    ushort4 v2 = *(const ushort4*)(msgs + (size_t)e4.z * 256 + lane * 4);
    ushort4 v3 = *(const ushort4*)(msgs + (size_t)e4.w * 256 + lane * 4);
    a0 += bf2f(v0.x) + bf2f(v1.x) + bf2f(v2.x) + bf2f(v3.x);
    a1 += bf2f(v0.y) + bf2f(v1.y) + bf2f(v2.y) + bf2f(v3.y);
    a2 += bf2f(v0.z) + bf2f(v1.z) + bf2f(v2.z) + bf2f(v3.z);
    a3 += bf2f(v0.w) + bf2f(v1.w) + bf2f(v2.w) + bf2f(v3.w);
  }
  for (; i < c; ++i) {
    int e = pl[i];
    ushort4 v = *(const ushort4*)(msgs + (size_t)e * 256 + lane * 4);
    a0 += bf2f(v.x); a1 += bf2f(v.y); a2 += bf2f(v.z); a3 += bf2f(v.w);
  }
  float fc = (float)c;
  float4 bv = *(const float4*)(b2 + lane * 4);
  float4 o;
  o.x = a0 + fc * bv.x; o.y = a1 + fc * bv.y;
  o.z = a2 + fc * bv.z; o.w = a3 + fc * bv.w;
  *(float4*)(out + (size_t)node * 256 + lane * 4) = o;
}

extern "C" void kernel_launch(void* const* d_in, const int* in_sizes, int n_in,
                              void* d_out, int out_size, void* d_ws, size_t ws_size,
                              hipStream_t stream) {
  const float* x_in      = (const float*)d_in[1];
  const int* EI          = (const int*)d_in[2];
  const float* edge_attr = (const float*)d_in[3];
  const float* W1        = (const float*)d_in[4];
  const float* b1        = (const float*)d_in[5];
  const float* W2        = (const float*)d_in[6];
  const float* b2        = (const float*)d_in[7];
  float* out = (float*)d_out;

  unsigned short* W1at = (unsigned short*)d_ws;
  unsigned short* W1bt = W1at + 512 * 256;
  unsigned short* W2t  = W1bt + 512 * 256;
  unsigned short* U    = W2t + 256 * 512;
  unsigned short* msgs = U + (size_t)N_NODES * 512;
  int* cnt  = (int*)(msgs + (size_t)E_EDGES * 256);
  int* perm = cnt + N_NODES;

  size_t need = ((size_t)(3 * 512 * 256) + (size_t)N_NODES * 512 + (size_t)E_EDGES * 256) * 2
              + ((size_t)N_NODES + (size_t)N_NODES * DEG_CAP) * 4;
  bool use_msgs = ws_size >= need;

  prep_kernel<<<1024, 256, 0, stream>>>(W1, W2, W1at, W1bt, W2t);
  if (use_msgs) {
    hipMemsetAsync(cnt, 0, (size_t)N_NODES * sizeof(int), stream);
    u_csr_kernel<<<628 + 1250, 256, 0, stream>>>(x_in, W1at, b1, U, EI, cnt, perm);
    main_kernel<1><<<E_EDGES / 32, 128, 0, stream>>>(EI, edge_attr, W1bt, W2t, U, b2, out, msgs);
    agg_kernel<<<N_NODES / 4, 256, 0, stream>>>(msgs, perm, cnt, b2, out);
  } else {
    hipMemsetAsync(d_out, 0, (size_t)out_size * sizeof(float), stream);
    u_csr_kernel<<<628, 256, 0, stream>>>(x_in, W1at, b1, U, EI, (int*)d_ws, (int*)d_ws);
    main_kernel<0><<<E_EDGES / 32, 128, 0, stream>>>(EI, edge_attr, W1bt, W2t, U, b2, out, msgs);
  }
}

// Round 3
// 959.982 us; speedup vs baseline: 1.2327x; 1.2327x over previous
//
#include <hip/hip_runtime.h>

#define E_EDGES 320000
#define N_NODES 10000
#define DEG_CAP 128

typedef __attribute__((ext_vector_type(8))) short bf16x8;
typedef __attribute__((ext_vector_type(4))) float f32x4;

// LDS-only barrier: make LDS ops visible WITHOUT draining vmcnt, so global
// prefetches (weights / U-gather) stay in flight across phase boundaries.
// (__syncthreads would emit s_waitcnt vmcnt(0) lgkmcnt(0) and flush them.)
#define LGKM_BAR() asm volatile("s_waitcnt lgkmcnt(0)\n\ts_barrier" ::: "memory")

__device__ __forceinline__ unsigned short f2bf(float x) {
  union { float f; unsigned u; } v; v.f = x;
  unsigned r = v.u + 0x7FFFu + ((v.u >> 16) & 1u);
  return (unsigned short)(r >> 16);
}
__device__ __forceinline__ float bf2f(unsigned short s) {
  union { unsigned u; float f; } v; v.u = ((unsigned)s) << 16;
  return v.f;
}

// ---------------- prep: W1 -> W1at/W1bt bf16 [n][k], W2 -> W2t bf16 [n][k] ----
__global__ __launch_bounds__(256) void prep_kernel(
    const float* __restrict__ W1, const float* __restrict__ W2,
    unsigned short* __restrict__ W1at, unsigned short* __restrict__ W1bt,
    unsigned short* __restrict__ W2t) {
  int tid = blockIdx.x * 256 + threadIdx.x;
  if (tid < 512 * 256) {
    int n = tid >> 8, k = tid & 255;          // W1at/W1bt: [512 n][256 k]
    W1at[tid] = f2bf(W1[k * 512 + n]);
    W1bt[tid] = f2bf(W1[(k + 256) * 512 + n]);
  } else {
    int t = tid - 512 * 256;
    if (t < 256 * 512) {
      int n = t >> 9, k = t & 511;            // W2t: [256 n][512 k]
      W2t[t] = f2bf(W2[k * 256 + n]);
    }
  }
}

// ---------------- U = x_in @ W1[0:256,:] + b1 (merged with CSR build) --------
__global__ __launch_bounds__(256) void u_csr_kernel(
    const float* __restrict__ x_in, const unsigned short* __restrict__ W1at,
    const float* __restrict__ b1, unsigned short* __restrict__ U,
    const int* __restrict__ EI, int* __restrict__ cnt, int* __restrict__ perm) {
  int b = blockIdx.x;
  if (b >= 628) {
    int e = (b - 628) * 256 + threadIdx.x;
    if (e < E_EDGES) {
      int d = EI[e];
      d = min(max(d, 0), N_NODES - 1);
      int p = atomicAdd(cnt + d, 1);
      if (p < DEG_CAP) perm[d * DEG_CAP + p] = e;
    }
    return;
  }
  int bx = b % 157, by = b / 157;
  __shared__ unsigned short x_lds[64 * 264];
  int tid = threadIdx.x;
  int m0g = bx * 64;
  for (int it = 0; it < 16; ++it) {
    int i = it * 256 + tid;
    int r = i >> 6, c = i & 63;
    int node = m0g + r;
    float4 v = make_float4(0.f, 0.f, 0.f, 0.f);
    if (node < N_NODES) v = *(const float4*)(x_in + node * 256 + c * 4);
    ushort4 s4;
    s4.x = f2bf(v.x); s4.y = f2bf(v.y); s4.z = f2bf(v.z); s4.w = f2bf(v.w);
    *(ushort4*)(x_lds + r * 264 + c * 4) = s4;
  }
  __syncthreads();
  int w = tid >> 6, l = tid & 63, quad = l >> 4, lid = l & 15;
  int cb = by * 128 + w * 32;
  f32x4 acc[2][4];
#pragma unroll
  for (int a = 0; a < 2; ++a)
#pragma unroll
    for (int c = 0; c < 4; ++c) acc[a][c] = (f32x4){0.f, 0.f, 0.f, 0.f};
  bf16x8 ac[2], an[2];
#pragma unroll
  for (int mf2 = 0; mf2 < 2; ++mf2)
    ac[mf2] = *(const bf16x8*)(W1at + (size_t)(cb + mf2 * 16 + lid) * 256 + quad * 8);
#pragma unroll
  for (int kk = 0; kk < 8; ++kk) {
    if (kk < 7) {
#pragma unroll
      for (int mf2 = 0; mf2 < 2; ++mf2)
        an[mf2] = *(const bf16x8*)(W1at + (size_t)(cb + mf2 * 16 + lid) * 256 + (kk + 1) * 32 + quad * 8);
    }
    bf16x8 xf[4];
#pragma unroll
    for (int nf2 = 0; nf2 < 4; ++nf2)
      xf[nf2] = *(const bf16x8*)(x_lds + (nf2 * 16 + lid) * 264 + kk * 32 + quad * 8);
#pragma unroll
    for (int mf2 = 0; mf2 < 2; ++mf2)
#pragma unroll
      for (int nf2 = 0; nf2 < 4; ++nf2)
        acc[mf2][nf2] = __builtin_amdgcn_mfma_f32_16x16x32_bf16(ac[mf2], xf[nf2], acc[mf2][nf2], 0, 0, 0);
#pragma unroll
    for (int mf2 = 0; mf2 < 2; ++mf2) ac[mf2] = an[mf2];
  }
#pragma unroll
  for (int mf2 = 0; mf2 < 2; ++mf2) {
    int colb = cb + mf2 * 16 + quad * 4;
    float4 bv = *(const float4*)(b1 + colb);
#pragma unroll
    for (int nf2 = 0; nf2 < 4; ++nf2) {
      int node = m0g + nf2 * 16 + lid;
      if (node < N_NODES) {
        ushort4 s4;
        s4.x = f2bf(acc[mf2][nf2][0] + bv.x);
        s4.y = f2bf(acc[mf2][nf2][1] + bv.y);
        s4.z = f2bf(acc[mf2][nf2][2] + bv.z);
        s4.w = f2bf(acc[mf2][nf2][3] + bv.w);
        *(ushort4*)(U + (size_t)node * 512 + colb) = s4;
      }
    }
  }
}

// ---------------- fused edge MLP: R1 geometry + vmcnt-preserving pipeline ----
#define EA_OFF 0            // 64 x 264 shorts = 33792 B
#define H_OFF  (64 * 264)   // 64 x 136 shorts = 17408 B
#define IDX_OFF (H_OFF + 64 * 136)  // 64 ints
template <int USE_MSGS>
__global__ __launch_bounds__(256, 3) void main_kernel(
    const int* __restrict__ EI, const float* __restrict__ edge_attr,
    const unsigned short* __restrict__ W1bt, const unsigned short* __restrict__ W2t,
    const unsigned short* __restrict__ U, const float* __restrict__ b2,
    float* __restrict__ out, unsigned short* __restrict__ msgs) {
  __shared__ unsigned short lds[64 * 264 + 64 * 136 + 128];
  int* idx_lds = (int*)(lds + IDX_OFF);

  int tid = threadIdx.x;
  int e0 = blockIdx.x * 64;
  int w = tid >> 6, l = tid & 63, quad = l >> 4, lid = l & 15;

  // ---- issued at entry: src indices (broadcast across quads via L1) ----
  int srcv[4];
#pragma unroll
  for (int nf2 = 0; nf2 < 4; ++nf2) {
    int s = EI[E_EDGES + e0 + nf2 * 16 + lid];
    srcv[nf2] = min(max(s, 0), N_NODES - 1);
  }
  // ---- issued at entry: nc=0 GEMM1 weight frags + U gather ----
  bf16x8 a1c[2], a1n[2];
#pragma unroll
  for (int mf2 = 0; mf2 < 2; ++mf2)
    a1c[mf2] = *(const bf16x8*)(W1bt + (size_t)(w * 32 + mf2 * 16 + lid) * 256 + quad * 8);
  ushort4 uq[2][4];
#pragma unroll
  for (int nf2 = 0; nf2 < 4; ++nf2) {
    const unsigned short* up = U + (size_t)srcv[nf2] * 512 + w * 32 + quad * 4;
#pragma unroll
    for (int mf2 = 0; mf2 < 2; ++mf2)
      uq[mf2][nf2] = *(const ushort4*)(up + mf2 * 16);
  }
  if (!USE_MSGS) {
    if (tid < 64) {
      int d = EI[e0 + tid];
      idx_lds[tid] = min(max(d, 0), N_NODES - 1);
    }
  }
  // ---- stage edge_attr -> bf16 LDS (coalesced float4, convert once) ----
  for (int it = 0; it < 16; ++it) {
    int i = it * 256 + tid;
    int r = i >> 6, c = i & 63;
    float4 v = *(const float4*)(edge_attr + (size_t)(e0 + r) * 256 + c * 4);
    ushort4 s4;
    s4.x = f2bf(v.x); s4.y = f2bf(v.y); s4.z = f2bf(v.z); s4.w = f2bf(v.w);
    *(ushort4*)(lds + EA_OFF + r * 264 + c * 4) = s4;
  }
  LGKM_BAR();

  f32x4 macc[4][4];   // [outcol-frag][edge-frag]
#pragma unroll
  for (int a = 0; a < 4; ++a)
#pragma unroll
    for (int c = 0; c < 4; ++c) macc[a][c] = (f32x4){0.f, 0.f, 0.f, 0.f};

  bf16x8 c2[4], n2[4];
  for (int nc = 0; nc < 4; ++nc) {
    int n0 = nc * 128;
    int arow = n0 + w * 32 + lid;
    int orow = w * 64 + lid;
    // ---- GEMM1b (swapped): acc1[hidden-frag][edge-frag] ----
    f32x4 acc1[2][4];
#pragma unroll
    for (int a = 0; a < 2; ++a)
#pragma unroll
      for (int c = 0; c < 4; ++c) acc1[a][c] = (f32x4){0.f, 0.f, 0.f, 0.f};
#pragma unroll
    for (int s = 0; s < 8; ++s) {
      if (s < 7) {
#pragma unroll
        for (int mf2 = 0; mf2 < 2; ++mf2)
          a1n[mf2] = *(const bf16x8*)(W1bt + (size_t)(arow + mf2 * 16) * 256 + (s + 1) * 32 + quad * 8);
      } else {
        // issue this chunk's GEMM2 weight frags; they ride across both barriers
#pragma unroll
        for (int nf = 0; nf < 4; ++nf)
          c2[nf] = *(const bf16x8*)(W2t + (size_t)(orow + nf * 16) * 512 + n0 + quad * 8);
      }
      int ka = s * 32 + quad * 8;
      bf16x8 ef[4];
#pragma unroll
      for (int nf2 = 0; nf2 < 4; ++nf2)
        ef[nf2] = *(const bf16x8*)(lds + EA_OFF + (nf2 * 16 + lid) * 264 + ka);
#pragma unroll
      for (int mf2 = 0; mf2 < 2; ++mf2)
#pragma unroll
        for (int nf2 = 0; nf2 < 4; ++nf2)
          acc1[mf2][nf2] = __builtin_amdgcn_mfma_f32_16x16x32_bf16(a1c[mf2], ef[nf2], acc1[mf2][nf2], 0, 0, 0);
      if (s < 7) {
#pragma unroll
        for (int mf2 = 0; mf2 < 2; ++mf2) a1c[mf2] = a1n[mf2];
      }
    }
    // ---- epilogue1: h = relu(acc1 + U[src]) (dep-stall only on uq) ----
    unsigned hp[2][4][2];
#pragma unroll
    for (int mf2 = 0; mf2 < 2; ++mf2)
#pragma unroll
      for (int nf2 = 0; nf2 < 4; ++nf2) {
        ushort4 u4 = uq[mf2][nf2];
        float h0 = acc1[mf2][nf2][0] + bf2f(u4.x);
        float h1 = acc1[mf2][nf2][1] + bf2f(u4.y);
        float h2 = acc1[mf2][nf2][2] + bf2f(u4.z);
        float h3 = acc1[mf2][nf2][3] + bf2f(u4.w);
        h0 = h0 > 0.f ? h0 : 0.f;
        h1 = h1 > 0.f ? h1 : 0.f;
        h2 = h2 > 0.f ? h2 : 0.f;
        h3 = h3 > 0.f ? h3 : 0.f;
        hp[mf2][nf2][0] = (unsigned)f2bf(h0) | ((unsigned)f2bf(h1) << 16);
        hp[mf2][nf2][1] = (unsigned)f2bf(h2) | ((unsigned)f2bf(h3) << 16);
      }
    LGKM_BAR();   // WAR: prev chunk's GEMM2 h-readers done (LDS only)
#pragma unroll
    for (int mf2 = 0; mf2 < 2; ++mf2)
#pragma unroll
      for (int nf2 = 0; nf2 < 4; ++nf2) {
        uint2 d;
        d.x = hp[mf2][nf2][0]; d.y = hp[mf2][nf2][1];
        *(uint2*)(lds + H_OFF + (nf2 * 16 + lid) * 136 + w * 32 + mf2 * 16 + quad * 4) = d;
      }
    LGKM_BAR();   // h visible (LDS only; c2 + next-nc loads stay in flight)
    // ---- issue next chunk's GEMM1 weights + U gather; hidden under GEMM2 ----
    if (nc < 3) {
      int arow2 = arow + 128;
#pragma unroll
      for (int mf2 = 0; mf2 < 2; ++mf2)
        a1c[mf2] = *(const bf16x8*)(W1bt + (size_t)(arow2 + mf2 * 16) * 256 + quad * 8);
#pragma unroll
      for (int nf2 = 0; nf2 < 4; ++nf2) {
        const unsigned short* up = U + (size_t)srcv[nf2] * 512 + (n0 + 128) + w * 32 + quad * 4;
#pragma unroll
        for (int mf2 = 0; mf2 < 2; ++mf2)
          uq[mf2][nf2] = *(const ushort4*)(up + mf2 * 16);
      }
    }
    // ---- GEMM2 (swapped): macc += W2t x h ----
#pragma unroll
    for (int s2 = 0; s2 < 4; ++s2) {
      if (s2 < 3) {
#pragma unroll
        for (int nf = 0; nf < 4; ++nf)
          n2[nf] = *(const bf16x8*)(W2t + (size_t)(orow + nf * 16) * 512 + n0 + (s2 + 1) * 32 + quad * 8);
      }
      int kl = s2 * 32 + quad * 8;
      bf16x8 hf[4];
#pragma unroll
      for (int nf2 = 0; nf2 < 4; ++nf2)
        hf[nf2] = *(const bf16x8*)(lds + H_OFF + (nf2 * 16 + lid) * 136 + kl);
#pragma unroll
      for (int mf2 = 0; mf2 < 4; ++mf2)
#pragma unroll
        for (int nf2 = 0; nf2 < 4; ++nf2)
          macc[mf2][nf2] = __builtin_amdgcn_mfma_f32_16x16x32_bf16(c2[mf2], hf[nf2], macc[mf2][nf2], 0, 0, 0);
      if (s2 < 3) {
#pragma unroll
        for (int nf = 0; nf < 4; ++nf) c2[nf] = n2[nf];
      }
    }
  }
  // ---- epilogue2 ----
  if (USE_MSGS) {
#pragma unroll
    for (int nf2 = 0; nf2 < 4; ++nf2) {
      size_t ebase = (size_t)(e0 + nf2 * 16 + lid) * 256;
#pragma unroll
      for (int mf2 = 0; mf2 < 4; ++mf2) {
        int col = w * 64 + mf2 * 16 + quad * 4;
        ushort4 s4;
        s4.x = f2bf(macc[mf2][nf2][0]);
        s4.y = f2bf(macc[mf2][nf2][1]);
        s4.z = f2bf(macc[mf2][nf2][2]);
        s4.w = f2bf(macc[mf2][nf2][3]);
        *(ushort4*)(msgs + ebase + col) = s4;
      }
    }
  } else {
#pragma unroll
    for (int mf2 = 0; mf2 < 4; ++mf2) {
      int col = w * 64 + mf2 * 16 + quad * 4;
      float4 bv = *(const float4*)(b2 + col);
#pragma unroll
      for (int nf2 = 0; nf2 < 4; ++nf2) {
        int node = idx_lds[nf2 * 16 + lid];
        float* op = out + (size_t)node * 256 + col;
        atomicAdd(op + 0, macc[mf2][nf2][0] + bv.x);
        atomicAdd(op + 1, macc[mf2][nf2][1] + bv.y);
        atomicAdd(op + 2, macc[mf2][nf2][2] + bv.z);
        atomicAdd(op + 3, macc[mf2][nf2][3] + bv.w);
      }
    }
  }
}

// ---------------- aggregation: wave-per-node, 4 gathers in flight ------------
__global__ __launch_bounds__(256) void agg_kernel(
    const unsigned short* __restrict__ msgs, const int* __restrict__ perm,
    const int* __restrict__ cnt, const float* __restrict__ b2,
    float* __restrict__ out) {
  int wv = threadIdx.x >> 6, lane = threadIdx.x & 63;
  int node = blockIdx.x * 4 + wv;
  int c = min(cnt[node], DEG_CAP);
  const int* pl = perm + node * DEG_CAP;
  float a0 = 0.f, a1 = 0.f, a2 = 0.f, a3 = 0.f;
  int i = 0;
  for (; i + 4 <= c; i += 4) {
    int4 e4 = *(const int4*)(pl + i);
    ushort4 v0 = *(const ushort4*)(msgs + (size_t)e4.x * 256 + lane * 4);
    ushort4 v1 = *(const ushort4*)(msgs + (size_t)e4.y * 256 + lane * 4);
    ushort4 v2 = *(const ushort4*)(msgs + (size_t)e4.z * 256 + lane * 4);
    ushort4 v3 = *(const ushort4*)(msgs + (size_t)e4.w * 256 + lane * 4);
    a0 += bf2f(v0.x) + bf2f(v1.x) + bf2f(v2.x) + bf2f(v3.x);
    a1 += bf2f(v0.y) + bf2f(v1.y) + bf2f(v2.y) + bf2f(v3.y);
    a2 += bf2f(v0.z) + bf2f(v1.z) + bf2f(v2.z) + bf2f(v3.z);
    a3 += bf2f(v0.w) + bf2f(v1.w) + bf2f(v2.w) + bf2f(v3.w);
  }
  for (; i < c; ++i) {
    int e = pl[i];
    ushort4 v = *(const ushort4*)(msgs + (size_t)e * 256 + lane * 4);
    a0 += bf2f(v.x); a1 += bf2f(v.y); a2 += bf2f(v.z); a3 += bf2f(v.w);
  }
  float fc = (float)c;
  float4 bv = *(const float4*)(b2 + lane * 4);
  float4 o;
  o.x = a0 + fc * bv.x; o.y = a1 + fc * bv.y;
  o.z = a2 + fc * bv.z; o.w = a3 + fc * bv.w;
  *(float4*)(out + (size_t)node * 256 + lane * 4) = o;
}

extern "C" void kernel_launch(void* const* d_in, const int* in_sizes, int n_in,
                              void* d_out, int out_size, void* d_ws, size_t ws_size,
                              hipStream_t stream) {
  const float* x_in      = (const float*)d_in[1];
  const int* EI          = (const int*)d_in[2];
  const float* edge_attr = (const float*)d_in[3];
  const float* W1        = (const float*)d_in[4];
  const float* b1        = (const float*)d_in[5];
  const float* W2        = (const float*)d_in[6];
  const float* b2        = (const float*)d_in[7];
  float* out = (float*)d_out;

  unsigned short* W1at = (unsigned short*)d_ws;
  unsigned short* W1bt = W1at + 512 * 256;
  unsigned short* W2t  = W1bt + 512 * 256;
  unsigned short* U    = W2t + 256 * 512;
  unsigned short* msgs = U + (size_t)N_NODES * 512;
  int* cnt  = (int*)(msgs + (size_t)E_EDGES * 256);
  int* perm = cnt + N_NODES;

  size_t need = ((size_t)(3 * 512 * 256) + (size_t)N_NODES * 512 + (size_t)E_EDGES * 256) * 2
              + ((size_t)N_NODES + (size_t)N_NODES * DEG_CAP) * 4;
  bool use_msgs = ws_size >= need;

  prep_kernel<<<1024, 256, 0, stream>>>(W1, W2, W1at, W1bt, W2t);
  if (use_msgs) {
    hipMemsetAsync(cnt, 0, (size_t)N_NODES * sizeof(int), stream);
    u_csr_kernel<<<628 + 1250, 256, 0, stream>>>(x_in, W1at, b1, U, EI, cnt, perm);
    main_kernel<1><<<E_EDGES / 64, 256, 0, stream>>>(EI, edge_attr, W1bt, W2t, U, b2, out, msgs);
    agg_kernel<<<N_NODES / 4, 256, 0, stream>>>(msgs, perm, cnt, b2, out);
  } else {
    hipMemsetAsync(d_out, 0, (size_t)out_size * sizeof(float), stream);
    u_csr_kernel<<<628, 256, 0, stream>>>(x_in, W1at, b1, U, EI, (int*)d_ws, (int*)d_ws);
    main_kernel<0><<<E_EDGES / 64, 256, 0, stream>>>(EI, edge_attr, W1bt, W2t, U, b2, out, msgs);
  }
}